// Round 2
// baseline (274.152 us; speedup 1.0000x reference)
//
#include <hip/hip_runtime.h>

#define Bsz 1024
#define Mm  2048
#define Rr  8192
#define EMAX 32   // max nz per E column (mean ~4.1, binomial tail => safe)
#define SMAX 64   // max nz per S row    (mean ~16.4, binomial tail => safe)

// Zero the count arrays (capture-safe: plain kernel, no hipMemsetAsync).
__global__ __launch_bounds__(256) void zero_counts(int* __restrict__ p, int n) {
    int i = blockIdx.x * blockDim.x + threadIdx.x;
    if (i < n) p[i] = 0;
}

// Pass 1: scan dense E,S (row-major [M,R]) with int4 loads, append nonzeros
// into transposed packed lists so the consumer reads them coalesced.
__global__ __launch_bounds__(256) void build_lists(
    const int* __restrict__ E, const int* __restrict__ S,
    int* __restrict__ ecnt, int* __restrict__ elist,
    int* __restrict__ scnt, int* __restrict__ slist)
{
    const int total4 = (Mm * Rr) / 4;
    const int stride = gridDim.x * blockDim.x;
    for (int vi = blockIdx.x * blockDim.x + threadIdx.x; vi < total4; vi += stride) {
        int4 e4 = ((const int4*)E)[vi];
        int4 s4 = ((const int4*)S)[vi];
        int base = vi << 2;
        int m = base >> 13;          // base / R
        int r = base & (Rr - 1);     // base % R  (same m for all 4 elements: R % 4 == 0)
        if (e4.x | e4.y | e4.z | e4.w) {
            int ev[4] = {e4.x, e4.y, e4.z, e4.w};
            #pragma unroll
            for (int u = 0; u < 4; ++u) {
                if (ev[u]) {
                    int slot = atomicAdd(&ecnt[r + u], 1);
                    if (slot < EMAX) elist[slot * Rr + (r + u)] = (ev[u] << 16) | m;
                }
            }
        }
        if (s4.x | s4.y | s4.z | s4.w) {
            int sv[4] = {s4.x, s4.y, s4.z, s4.w};
            #pragma unroll
            for (int u = 0; u < 4; ++u) {
                if (sv[u]) {
                    int slot = atomicAdd(&scnt[m], 1);
                    if (slot < SMAX) slist[slot * Mm + m] = (sv[u] << 16) | (r + u);
                }
            }
        }
    }
}

// Pass 2: one block per batch row b.
//   A) logc row -> LDS (8 KB)
//   B) v[r] = k[r] * exp(sum_e e*logc[m]) -> LDS (32 KB)
//   C) dXdt[b,m] = sum_s s*v[r] -> global (coalesced)
__global__ __launch_bounds__(256) void kinetic_main(
    const float* __restrict__ conc, const float* __restrict__ kvec,
    const int* __restrict__ ecnt, const int* __restrict__ elist,
    const int* __restrict__ scnt, const int* __restrict__ slist,
    float* __restrict__ out)
{
    __shared__ float logc[Mm];   // 8 KB
    __shared__ float vsh[Rr];    // 32 KB  -> 40 KB total, 4 blocks/CU
    const int b = blockIdx.x;
    const int t = threadIdx.x;

    const float4* c4 = (const float4*)(conc + (size_t)b * Mm);
    for (int i = t; i < Mm / 4; i += 256) {
        float4 c = c4[i];
        logc[4 * i + 0] = __logf(c.x);
        logc[4 * i + 1] = __logf(c.y);
        logc[4 * i + 2] = __logf(c.z);
        logc[4 * i + 3] = __logf(c.w);
    }
    __syncthreads();

    for (int r = t; r < Rr; r += 256) {
        int cnt = min(ecnt[r], EMAX);
        float s = 0.f;
        for (int j = 0; j < cnt; ++j) {
            int w = elist[j * Rr + r];           // coalesced across lanes
            s += (float)(w >> 16) * logc[w & 0xFFFF];
        }
        vsh[r] = kvec[r] * __expf(s);
    }
    __syncthreads();

    for (int m = t; m < Mm; m += 256) {
        int cnt = min(scnt[m], SMAX);
        float acc = 0.f;
        for (int j = 0; j < cnt; ++j) {
            int w = slist[j * Mm + m];           // coalesced across lanes
            acc += (float)(w >> 16) * vsh[w & 0xFFFF];  // signed s via arith >>16
        }
        out[(size_t)b * Mm + m] = acc;
    }
}

extern "C" void kernel_launch(void* const* d_in, const int* in_sizes, int n_in,
                              void* d_out, int out_size, void* d_ws, size_t ws_size,
                              hipStream_t stream) {
    const float* conc = (const float*)d_in[0];
    const int*   E    = (const int*)d_in[1];
    const int*   S    = (const int*)d_in[2];
    const float* kvec = (const float*)d_in[3];
    float* out = (float*)d_out;

    // workspace layout (re-poisoned every call, so rebuild every call)
    int* ecnt  = (int*)d_ws;              // R
    int* scnt  = ecnt + Rr;               // M
    int* elist = scnt + Mm;               // EMAX * R
    int* slist = elist + EMAX * Rr;       // SMAX * M
    const size_t need = (size_t)(Rr + Mm + EMAX * Rr + SMAX * Mm) * sizeof(int); // ~1.6 MB
    if (ws_size < need) return;  // degrade to a numeric failure, never an OOB fault

    zero_counts<<<(Rr + Mm + 255) / 256, 256, 0, stream>>>(ecnt, Rr + Mm);
    build_lists<<<4096, 256, 0, stream>>>(E, S, ecnt, elist, scnt, slist);
    kinetic_main<<<Bsz, 256, 0, stream>>>(conc, kvec, ecnt, elist, scnt, slist, out);
}

// Round 3
// 263.508 us; speedup vs baseline: 1.0404x; 1.0404x over previous
//
#include <hip/hip_runtime.h>

#define Bsz 1024
#define Mm  2048
#define Rr  8192
#define EMAX 32   // slots per E column (mean nnz ~4.1)
#define SMAX 64   // slots per S row    (mean nnz ~16.4)
#define RCHUNK 32
#define MCHUNK 8

// ---- zero the count arrays (capture-safe plain kernel) ----
__global__ __launch_bounds__(256) void zero_counts(int* __restrict__ p, int n) {
    int i = blockIdx.x * blockDim.x + threadIdx.x;
    if (i < n) p[i] = 0;
}

// ---- pass 1: dense scan of E,S -> compact per-r / per-m lists ----
__global__ __launch_bounds__(256) void build_lists(
    const int* __restrict__ E, const int* __restrict__ S,
    int* __restrict__ ecnt, int* __restrict__ elist,
    int* __restrict__ scnt, int* __restrict__ slist)
{
    const int total4 = (Mm * Rr) / 4;
    const int stride = gridDim.x * blockDim.x;
    for (int vi = blockIdx.x * blockDim.x + threadIdx.x; vi < total4; vi += stride) {
        int4 e4 = ((const int4*)E)[vi];
        int4 s4 = ((const int4*)S)[vi];
        int base = vi << 2;
        int m = base >> 13;          // base / R
        int r = base & (Rr - 1);     // base % R (R % 4 == 0 so same m for all 4)
        if (e4.x | e4.y | e4.z | e4.w) {
            int ev[4] = {e4.x, e4.y, e4.z, e4.w};
            #pragma unroll
            for (int u = 0; u < 4; ++u)
                if (ev[u]) {
                    int slot = atomicAdd(&ecnt[r + u], 1);
                    if (slot < EMAX) elist[(r + u) * EMAX + slot] = (ev[u] << 16) | m;
                }
        }
        if (s4.x | s4.y | s4.z | s4.w) {
            int sv[4] = {s4.x, s4.y, s4.z, s4.w};
            #pragma unroll
            for (int u = 0; u < 4; ++u)
                if (sv[u]) {
                    int slot = atomicAdd(&scnt[m], 1);
                    if (slot < SMAX) slist[m * SMAX + slot] = (sv[u] << 16) | (r + u);
                }
        }
    }
}

// ---- pass 2: logcT[m][b] = log(conc[b][m]), tiled 64x64 transpose ----
__global__ __launch_bounds__(256) void transpose_log(
    const float* __restrict__ conc, float* __restrict__ logcT)
{
    __shared__ float tile[64][65];
    const int mt = (blockIdx.x % (Mm / 64)) * 64;
    const int bt = (blockIdx.x / (Mm / 64)) * 64;
    const int lm = threadIdx.x & 63;     // lane -> m offset (coalesced reads)
    const int w  = threadIdx.x >> 6;     // wave id 0..3
    for (int i = w; i < 64; i += 4)
        tile[lm][i] = __logf(conc[(size_t)(bt + i) * Mm + mt + lm]);
    __syncthreads();
    for (int i = w; i < 64; i += 4)
        logcT[(size_t)(mt + i) * Bsz + bt + lm] = tile[i][lm];
}

// ---- pass 3: VT[r][b] = k[r] * exp(sum_j e_j * logcT[m_j][b]) ----
// lanes = b (coalesced); r & list entries wave-uniform (scalar loads, no divergence)
__global__ __launch_bounds__(256) void rates_kernel(
    const float* __restrict__ logcT, const float* __restrict__ kvec,
    const int* __restrict__ ecnt, const int* __restrict__ elist,
    float* __restrict__ VT)
{
    const int rblk = blockIdx.x & 255;                     // 8192/RCHUNK = 256
    const int b    = (blockIdx.x >> 8) * 256 + threadIdx.x;
    const int r0   = rblk * RCHUNK;
    for (int rr = 0; rr < RCHUNK; ++rr) {
        const int r   = r0 + rr;
        const int cnt = min(ecnt[r], EMAX);
        float s = 0.f;
        for (int j = 0; j < cnt; ++j) {
            int w = elist[r * EMAX + j];                   // wave-uniform
            s += (float)(w >> 16) * logcT[(size_t)(w & 0xFFFF) * Bsz + b];
        }
        VT[(size_t)r * Bsz + b] = kvec[r] * __expf(s);
    }
}

// ---- pass 4: out[b][m] = sum_j s_j * VT[r_j][b]; LDS transpose for stores ----
__global__ __launch_bounds__(256) void assemble_kernel(
    const float* __restrict__ VT,
    const int* __restrict__ scnt, const int* __restrict__ slist,
    float* __restrict__ out)
{
    __shared__ float tile[MCHUNK][257];
    const int mblk = blockIdx.x & 255;                     // 2048/MCHUNK = 256
    const int bt   = (blockIdx.x >> 8) * 256;
    const int t    = threadIdx.x;
    const int m0   = mblk * MCHUNK;
    for (int mm = 0; mm < MCHUNK; ++mm) {
        const int m   = m0 + mm;
        const int cnt = min(scnt[m], SMAX);
        float acc = 0.f;
        for (int j = 0; j < cnt; ++j) {
            int w = slist[m * SMAX + j];                   // wave-uniform
            acc += (float)(w >> 16) * VT[(size_t)(w & 0xFFFF) * Bsz + bt + t];
        }
        tile[mm][t] = acc;
    }
    __syncthreads();
    float vals[MCHUNK];
    #pragma unroll
    for (int mm = 0; mm < MCHUNK; ++mm) vals[mm] = tile[mm][t];
    float4* o = (float4*)(out + (size_t)(bt + t) * Mm + m0);
    o[0] = make_float4(vals[0], vals[1], vals[2], vals[3]);
    o[1] = make_float4(vals[4], vals[5], vals[6], vals[7]);
}

// ---- fallback fused kernel (used only if ws too small for VT/logcT) ----
__global__ __launch_bounds__(256) void kinetic_fused(
    const float* __restrict__ conc, const float* __restrict__ kvec,
    const int* __restrict__ ecnt, const int* __restrict__ elist,
    const int* __restrict__ scnt, const int* __restrict__ slist,
    float* __restrict__ out)
{
    __shared__ float logc[Mm];
    __shared__ float vsh[Rr];
    const int b = blockIdx.x, t = threadIdx.x;
    const float4* c4 = (const float4*)(conc + (size_t)b * Mm);
    for (int i = t; i < Mm / 4; i += 256) {
        float4 c = c4[i];
        logc[4*i+0] = __logf(c.x); logc[4*i+1] = __logf(c.y);
        logc[4*i+2] = __logf(c.z); logc[4*i+3] = __logf(c.w);
    }
    __syncthreads();
    for (int r = t; r < Rr; r += 256) {
        int cnt = min(ecnt[r], EMAX);
        float s = 0.f;
        for (int j = 0; j < cnt; ++j) {
            int w = elist[r * EMAX + j];
            s += (float)(w >> 16) * logc[w & 0xFFFF];
        }
        vsh[r] = kvec[r] * __expf(s);
    }
    __syncthreads();
    for (int m = t; m < Mm; m += 256) {
        int cnt = min(scnt[m], SMAX);
        float acc = 0.f;
        for (int j = 0; j < cnt; ++j) {
            int w = slist[m * SMAX + j];
            acc += (float)(w >> 16) * vsh[w & 0xFFFF];
        }
        out[(size_t)b * Mm + m] = acc;
    }
}

extern "C" void kernel_launch(void* const* d_in, const int* in_sizes, int n_in,
                              void* d_out, int out_size, void* d_ws, size_t ws_size,
                              hipStream_t stream) {
    const float* conc = (const float*)d_in[0];
    const int*   E    = (const int*)d_in[1];
    const int*   S    = (const int*)d_in[2];
    const float* kvec = (const float*)d_in[3];
    float* out = (float*)d_out;

    // ws layout: VT (32 MB) | logcT (8 MB) | ecnt | scnt | elist | slist
    float* VT    = (float*)d_ws;
    float* logcT = VT + (size_t)Rr * Bsz;
    int*   ecnt  = (int*)(logcT + (size_t)Mm * Bsz);
    int*   scnt  = ecnt + Rr;
    int*   elist = scnt + Mm;
    int*   slist = elist + Rr * EMAX;
    const size_t need_lists = (size_t)(Rr + Mm + Rr * EMAX + Mm * SMAX) * sizeof(int);
    const size_t need_full  = ((size_t)Rr * Bsz + (size_t)Mm * Bsz) * sizeof(float) + need_lists;

    if (ws_size >= need_full) {
        zero_counts<<<(Rr + Mm + 255) / 256, 256, 0, stream>>>(ecnt, Rr + Mm);
        build_lists<<<8192, 256, 0, stream>>>(E, S, ecnt, elist, scnt, slist);
        transpose_log<<<(Mm / 64) * (Bsz / 64), 256, 0, stream>>>(conc, logcT);
        rates_kernel<<<(Rr / RCHUNK) * (Bsz / 256), 256, 0, stream>>>(logcT, kvec, ecnt, elist, VT);
        assemble_kernel<<<(Mm / MCHUNK) * (Bsz / 256), 256, 0, stream>>>(VT, scnt, slist, out);
    } else if (ws_size >= need_lists) {
        int* ecnt2  = (int*)d_ws;
        int* scnt2  = ecnt2 + Rr;
        int* elist2 = scnt2 + Mm;
        int* slist2 = elist2 + Rr * EMAX;
        zero_counts<<<(Rr + Mm + 255) / 256, 256, 0, stream>>>(ecnt2, Rr + Mm);
        build_lists<<<8192, 256, 0, stream>>>(E, S, ecnt2, elist2, scnt2, slist2);
        kinetic_fused<<<Bsz, 256, 0, stream>>>(conc, kvec, ecnt2, elist2, scnt2, slist2, out);
    }
}

// Round 4
// 219.590 us; speedup vs baseline: 1.2485x; 1.2000x over previous
//
#include <hip/hip_runtime.h>

#define Bsz 1024
#define Mm  2048
#define Rr  8192
#define EMAX 32   // slots per E column (mean nnz ~4.1)
#define SMAX 64   // slots per S row    (mean nnz ~16.4)
#define RCHUNK 16
#define MCHUNK 4

// ---- pass 1: logcT[m][b] = log(conc[b][m]) (tiled transpose); also zeroes counts ----
__global__ __launch_bounds__(256) void transpose_log(
    const float* __restrict__ conc, float* __restrict__ logcT,
    int* __restrict__ cnts /* ecnt||scnt, Rr+Mm ints */)
{
    int g = blockIdx.x * 256 + threadIdx.x;
    if (g < Rr + Mm) cnts[g] = 0;               // grid 512*256 = 131072 >= 10240
    __shared__ float tile[64][65];
    const int mt = (blockIdx.x % (Mm / 64)) * 64;
    const int bt = (blockIdx.x / (Mm / 64)) * 64;
    const int lm = threadIdx.x & 63;
    const int w  = threadIdx.x >> 6;
    for (int i = w; i < 64; i += 4)
        tile[lm][i] = __logf(conc[(size_t)(bt + i) * Mm + mt + lm]);
    __syncthreads();
    for (int i = w; i < 64; i += 4)
        logcT[(size_t)(mt + i) * Bsz + bt + lm] = tile[i][lm];
}

// ---- pass 2: dense scan of E,S -> compact lists; 8 loads in flight per thread ----
__global__ __launch_bounds__(256) void build_lists(
    const int* __restrict__ E, const int* __restrict__ S,
    int* __restrict__ ecnt, int* __restrict__ elist,
    int* __restrict__ scnt, int* __restrict__ slist)
{
    const int4* E4 = (const int4*)E;
    const int4* S4 = (const int4*)S;
    const int vi0 = blockIdx.x * 1024 + threadIdx.x;   // grid 4096: covers Mm*Rr/4 = 4M
    int4 e[4], s[4];
    #pragma unroll
    for (int u = 0; u < 4; ++u) e[u] = E4[vi0 + 256 * u];
    #pragma unroll
    for (int u = 0; u < 4; ++u) s[u] = S4[vi0 + 256 * u];
    #pragma unroll
    for (int u = 0; u < 4; ++u) {
        const int base = (vi0 + 256 * u) << 2;
        const int m = base >> 13;          // base / R
        const int r = base & (Rr - 1);     // base % R (same m for all 4: R%4==0)
        int ev[4] = {e[u].x, e[u].y, e[u].z, e[u].w};
        int sv[4] = {s[u].x, s[u].y, s[u].z, s[u].w};
        if (ev[0] | ev[1] | ev[2] | ev[3]) {
            #pragma unroll
            for (int q = 0; q < 4; ++q)
                if (ev[q]) {
                    int slot = atomicAdd(&ecnt[r + q], 1);
                    if (slot < EMAX) elist[(r + q) * EMAX + slot] = (ev[q] << 16) | m;
                }
        }
        if (sv[0] | sv[1] | sv[2] | sv[3]) {
            #pragma unroll
            for (int q = 0; q < 4; ++q)
                if (sv[q]) {
                    int slot = atomicAdd(&scnt[m], 1);
                    if (slot < SMAX) slist[m * SMAX + slot] = (sv[q] << 16) | (r + q);
                }
        }
    }
}

// ---- pass 3: VT[r][b] = k[r]*exp(sum e*logcT[m][b]); 4 gathers in flight ----
__global__ __launch_bounds__(256) void rates_kernel(
    const float* __restrict__ logcT, const float* __restrict__ kvec,
    const int* __restrict__ ecnt, const int* __restrict__ elist,
    float* __restrict__ VT)
{
    const int rblk = blockIdx.x & 511;                   // Rr/RCHUNK = 512
    const int b    = (blockIdx.x >> 9) * 256 + threadIdx.x;
    for (int rr = 0; rr < RCHUNK; ++rr) {
        const int r   = rblk * RCHUNK + rr;
        const int cnt = min(ecnt[r], EMAX);
        const int* row = elist + r * EMAX;               // wave-uniform
        float s = 0.f;
        int j = 0;
        for (; j + 4 <= cnt; j += 4) {
            int4 w = *(const int4*)(row + j);            // s_load_dwordx4
            float c0 = logcT[(size_t)(w.x & 0xFFFF) * Bsz + b];
            float c1 = logcT[(size_t)(w.y & 0xFFFF) * Bsz + b];
            float c2 = logcT[(size_t)(w.z & 0xFFFF) * Bsz + b];
            float c3 = logcT[(size_t)(w.w & 0xFFFF) * Bsz + b];
            s += (float)(w.x >> 16) * c0 + (float)(w.y >> 16) * c1
               + (float)(w.z >> 16) * c2 + (float)(w.w >> 16) * c3;
        }
        for (; j < cnt; ++j) {
            int w = row[j];
            s += (float)(w >> 16) * logcT[(size_t)(w & 0xFFFF) * Bsz + b];
        }
        VT[(size_t)r * Bsz + b] = kvec[r] * __expf(s);
    }
}

// ---- pass 4: out[b][m] = sum s*VT[r][b]; 4 gathers in flight, float4 store ----
__global__ __launch_bounds__(256) void assemble_kernel(
    const float* __restrict__ VT,
    const int* __restrict__ scnt, const int* __restrict__ slist,
    float* __restrict__ out)
{
    const int mblk = blockIdx.x & 511;                   // Mm/MCHUNK = 512
    const int bt   = (blockIdx.x >> 9) * 256;
    const int t    = threadIdx.x;
    const int m0   = mblk * MCHUNK;
    float acc[MCHUNK];
    #pragma unroll
    for (int mm = 0; mm < MCHUNK; ++mm) {
        const int m   = m0 + mm;
        const int cnt = min(scnt[m], SMAX);
        const int* row = slist + m * SMAX;               // wave-uniform
        float a = 0.f;
        int j = 0;
        for (; j + 4 <= cnt; j += 4) {
            int4 w = *(const int4*)(row + j);            // s_load_dwordx4
            float v0 = VT[(size_t)(w.x & 0xFFFF) * Bsz + bt + t];
            float v1 = VT[(size_t)(w.y & 0xFFFF) * Bsz + bt + t];
            float v2 = VT[(size_t)(w.z & 0xFFFF) * Bsz + bt + t];
            float v3 = VT[(size_t)(w.w & 0xFFFF) * Bsz + bt + t];
            a += (float)(w.x >> 16) * v0 + (float)(w.y >> 16) * v1
               + (float)(w.z >> 16) * v2 + (float)(w.w >> 16) * v3;
        }
        for (; j < cnt; ++j) {
            int w = row[j];
            a += (float)(w >> 16) * VT[(size_t)(w & 0xFFFF) * Bsz + bt + t];
        }
        acc[mm] = a;
    }
    *(float4*)(out + (size_t)(bt + t) * Mm + m0) =
        make_float4(acc[0], acc[1], acc[2], acc[3]);
}

// ---- fallback fused kernel (only if ws too small for VT/logcT) ----
__global__ __launch_bounds__(256) void kinetic_fused(
    const float* __restrict__ conc, const float* __restrict__ kvec,
    const int* __restrict__ ecnt, const int* __restrict__ elist,
    const int* __restrict__ scnt, const int* __restrict__ slist,
    float* __restrict__ out)
{
    __shared__ float logc[Mm];
    __shared__ float vsh[Rr];
    const int b = blockIdx.x, t = threadIdx.x;
    const float4* c4 = (const float4*)(conc + (size_t)b * Mm);
    for (int i = t; i < Mm / 4; i += 256) {
        float4 c = c4[i];
        logc[4*i+0] = __logf(c.x); logc[4*i+1] = __logf(c.y);
        logc[4*i+2] = __logf(c.z); logc[4*i+3] = __logf(c.w);
    }
    __syncthreads();
    for (int r = t; r < Rr; r += 256) {
        int cnt = min(ecnt[r], EMAX);
        float s = 0.f;
        for (int j = 0; j < cnt; ++j) {
            int w = elist[r * EMAX + j];
            s += (float)(w >> 16) * logc[w & 0xFFFF];
        }
        vsh[r] = kvec[r] * __expf(s);
    }
    __syncthreads();
    for (int m = t; m < Mm; m += 256) {
        int cnt = min(scnt[m], SMAX);
        float acc = 0.f;
        for (int j = 0; j < cnt; ++j) {
            int w = slist[m * SMAX + j];
            acc += (float)(w >> 16) * vsh[w & 0xFFFF];
        }
        out[(size_t)b * Mm + m] = acc;
    }
}

extern "C" void kernel_launch(void* const* d_in, const int* in_sizes, int n_in,
                              void* d_out, int out_size, void* d_ws, size_t ws_size,
                              hipStream_t stream) {
    const float* conc = (const float*)d_in[0];
    const int*   E    = (const int*)d_in[1];
    const int*   S    = (const int*)d_in[2];
    const float* kvec = (const float*)d_in[3];
    float* out = (float*)d_out;

    // ws layout: VT (32 MB) | logcT (8 MB) | ecnt | scnt | elist | slist
    float* VT    = (float*)d_ws;
    float* logcT = VT + (size_t)Rr * Bsz;
    int*   ecnt  = (int*)(logcT + (size_t)Mm * Bsz);
    int*   scnt  = ecnt + Rr;
    int*   elist = scnt + Mm;
    int*   slist = elist + Rr * EMAX;
    const size_t need_lists = (size_t)(Rr + Mm + Rr * EMAX + Mm * SMAX) * sizeof(int);
    const size_t need_full  = ((size_t)Rr * Bsz + (size_t)Mm * Bsz) * sizeof(float) + need_lists;

    if (ws_size >= need_full) {
        transpose_log<<<(Mm / 64) * (Bsz / 64), 256, 0, stream>>>(conc, logcT, ecnt);
        build_lists<<<(Mm * Rr / 4) / 1024, 256, 0, stream>>>(E, S, ecnt, elist, scnt, slist);
        rates_kernel<<<(Rr / RCHUNK) * (Bsz / 256), 256, 0, stream>>>(logcT, kvec, ecnt, elist, VT);
        assemble_kernel<<<(Mm / MCHUNK) * (Bsz / 256), 256, 0, stream>>>(VT, scnt, slist, out);
    } else if (ws_size >= need_lists) {
        int* ecnt2  = (int*)d_ws;
        int* scnt2  = ecnt2 + Rr;
        int* elist2 = scnt2 + Mm;
        int* slist2 = elist2 + Rr * EMAX;
        // zero via transpose-less path: reuse build grid to zero first
        hipMemsetAsync(ecnt2, 0, (Rr + Mm) * sizeof(int), stream);
        build_lists<<<(Mm * Rr / 4) / 1024, 256, 0, stream>>>(E, S, ecnt2, elist2, scnt2, slist2);
        kinetic_fused<<<Bsz, 256, 0, stream>>>(conc, kvec, ecnt2, elist2, scnt2, slist2, out);
    }
}

// Round 5
// 207.609 us; speedup vs baseline: 1.3205x; 1.0577x over previous
//
#include <hip/hip_runtime.h>
#include <hip/hip_fp16.h>

#define Bsz 1024
#define Mm  2048
#define Rr  8192
#define EMAX 32   // slots per E column (mean nnz ~4.1)
#define SMAX 64   // slots per S row    (mean nnz ~16.4)

// ---- pass 1: logcT[m][b] = log(conc[b][m]); also zeroes counts + BOTH lists ----
// grid 512 x 256 = 131072 threads; zero work: 10240 cnts + 98304 int4 list slots
__global__ __launch_bounds__(256) void transpose_log(
    const float* __restrict__ conc, float* __restrict__ logcT,
    int* __restrict__ cnts, int4* __restrict__ elist4, int4* __restrict__ slist4)
{
    const int g = blockIdx.x * 256 + threadIdx.x;
    if (g < Rr + Mm) cnts[g] = 0;
    if (g < (Rr * EMAX) / 4) elist4[g] = make_int4(0, 0, 0, 0);
    if (g < (Mm * SMAX) / 4) slist4[g] = make_int4(0, 0, 0, 0);

    __shared__ float tile[64][65];
    const int mt = (blockIdx.x % (Mm / 64)) * 64;
    const int bt = (blockIdx.x / (Mm / 64)) * 64;
    const int lm = threadIdx.x & 63;
    const int w  = threadIdx.x >> 6;
    for (int i = w; i < 64; i += 4)
        tile[lm][i] = __logf(conc[(size_t)(bt + i) * Mm + mt + lm]);
    __syncthreads();
    for (int i = w; i < 64; i += 4)
        logcT[(size_t)(mt + i) * Bsz + bt + lm] = tile[i][lm];
}

// ---- pass 2: dense scan of E,S -> compact lists; 16 int4 loads in flight ----
// grid 2048 blocks; block b covers exactly m-row b (2048 int4 per row)
__global__ __launch_bounds__(256) void build_lists(
    const int* __restrict__ E, const int* __restrict__ S,
    int* __restrict__ ecnt, int* __restrict__ elist,
    int* __restrict__ scnt, int* __restrict__ slist)
{
    const int4* E4 = (const int4*)E;
    const int4* S4 = (const int4*)S;
    const int vi0 = blockIdx.x * 2048 + threadIdx.x;
    const int m   = blockIdx.x;                 // one m row per block
    int4 e[8], s[8];
    #pragma unroll
    for (int u = 0; u < 8; ++u) e[u] = E4[vi0 + 256 * u];
    #pragma unroll
    for (int u = 0; u < 8; ++u) s[u] = S4[vi0 + 256 * u];
    #pragma unroll
    for (int u = 0; u < 8; ++u) {
        const int r = ((vi0 + 256 * u) << 2) & (Rr - 1);
        int ev[4] = {e[u].x, e[u].y, e[u].z, e[u].w};
        int sv[4] = {s[u].x, s[u].y, s[u].z, s[u].w};
        if (ev[0] | ev[1] | ev[2] | ev[3]) {
            #pragma unroll
            for (int q = 0; q < 4; ++q)
                if (ev[q]) {
                    int slot = atomicAdd(&ecnt[r + q], 1);
                    if (slot < EMAX) elist[(r + q) * EMAX + slot] = (ev[q] << 16) | m;
                }
        }
        if (sv[0] | sv[1] | sv[2] | sv[3]) {
            #pragma unroll
            for (int q = 0; q < 4; ++q)
                if (sv[q]) {
                    int slot = atomicAdd(&scnt[m], 1);
                    if (slot < SMAX) slist[m * SMAX + slot] = (sv[q] << 16) | (r + q);
                }
        }
    }
}

// ---- pass 3: VT[r][b] (fp16) = k[r]*exp(sum e*logcT[m][b]) ----
// b-tile 512 via float2; r-pairs -> 16 float2 gathers in flight. grid 2048.
__global__ __launch_bounds__(256) void rates_kernel(
    const float* __restrict__ logcT, const float* __restrict__ kvec,
    const int* __restrict__ ecnt, const int* __restrict__ elist,
    __half2* __restrict__ VTh)
{
    const int rblk = blockIdx.x & 1023;          // Rr/8 = 1024
    const int bg   = blockIdx.x >> 10;           // 0..1
    const int b2   = bg * 256 + threadIdx.x;     // float2/half2 column index
    const float2* LC = (const float2*)logcT;     // row pitch 512

    for (int rr = 0; rr < 8; rr += 2) {
        const int r0 = rblk * 8 + rr, r1 = r0 + 1;
        const int* row0 = elist + (r0 << 5);
        const int* row1 = elist + (r1 << 5);
        int4 a0 = *(const int4*)(row0);
        int4 a1 = *(const int4*)(row0 + 4);
        int4 b0 = *(const int4*)(row1);
        int4 b1 = *(const int4*)(row1 + 4);
        float2 g[8], h[8];
        g[0] = LC[((a0.x & 0xFFFF) << 9) + b2];
        g[1] = LC[((a0.y & 0xFFFF) << 9) + b2];
        g[2] = LC[((a0.z & 0xFFFF) << 9) + b2];
        g[3] = LC[((a0.w & 0xFFFF) << 9) + b2];
        g[4] = LC[((a1.x & 0xFFFF) << 9) + b2];
        g[5] = LC[((a1.y & 0xFFFF) << 9) + b2];
        g[6] = LC[((a1.z & 0xFFFF) << 9) + b2];
        g[7] = LC[((a1.w & 0xFFFF) << 9) + b2];
        h[0] = LC[((b0.x & 0xFFFF) << 9) + b2];
        h[1] = LC[((b0.y & 0xFFFF) << 9) + b2];
        h[2] = LC[((b0.z & 0xFFFF) << 9) + b2];
        h[3] = LC[((b0.w & 0xFFFF) << 9) + b2];
        h[4] = LC[((b1.x & 0xFFFF) << 9) + b2];
        h[5] = LC[((b1.y & 0xFFFF) << 9) + b2];
        h[6] = LC[((b1.z & 0xFFFF) << 9) + b2];
        h[7] = LC[((b1.w & 0xFFFF) << 9) + b2];
        float2 s0 = make_float2(0.f, 0.f), s1 = make_float2(0.f, 0.f);
        int wt[8] = {a0.x >> 16, a0.y >> 16, a0.z >> 16, a0.w >> 16,
                     a1.x >> 16, a1.y >> 16, a1.z >> 16, a1.w >> 16};
        int vt[8] = {b0.x >> 16, b0.y >> 16, b0.z >> 16, b0.w >> 16,
                     b1.x >> 16, b1.y >> 16, b1.z >> 16, b1.w >> 16};
        #pragma unroll
        for (int j = 0; j < 8; ++j) {
            s0.x += (float)wt[j] * g[j].x;  s0.y += (float)wt[j] * g[j].y;
            s1.x += (float)vt[j] * h[j].x;  s1.y += (float)vt[j] * h[j].y;
        }
        int cA = min(ecnt[r0], EMAX);                 // wave-uniform tails (rare)
        if (cA > 8)
            for (int j = 8; j < cA; ++j) {
                int w = row0[j];
                float2 gv = LC[((w & 0xFFFF) << 9) + b2];
                float wf = (float)(w >> 16);
                s0.x += wf * gv.x;  s0.y += wf * gv.y;
            }
        int cB = min(ecnt[r1], EMAX);
        if (cB > 8)
            for (int j = 8; j < cB; ++j) {
                int w = row1[j];
                float2 gv = LC[((w & 0xFFFF) << 9) + b2];
                float wf = (float)(w >> 16);
                s1.x += wf * gv.x;  s1.y += wf * gv.y;
            }
        float k0 = kvec[r0], k1 = kvec[r1];
        VTh[(r0 << 9) + b2] = __floats2half2_rn(k0 * __expf(s0.x), k0 * __expf(s0.y));
        VTh[(r1 << 9) + b2] = __floats2half2_rn(k1 * __expf(s1.x), k1 * __expf(s1.y));
    }
}

// ---- pass 4: out[b][m] = sum s*VT[r][b]; 16 half2 gathers in flight. grid 1024 ----
__global__ __launch_bounds__(256) void assemble_kernel(
    const __half2* __restrict__ VTh,
    const int* __restrict__ scnt, const int* __restrict__ slist,
    float* __restrict__ out)
{
    const int mblk = blockIdx.x & 511;           // Mm/4 = 512
    const int bg   = blockIdx.x >> 9;            // 0..1
    const int b2   = bg * 256 + threadIdx.x;
    const int m0   = mblk * 4;
    float2 acc[4];
    #pragma unroll
    for (int mm = 0; mm < 4; ++mm) {
        const int m = m0 + mm;
        const int* row = slist + (m << 6);
        int4 w0 = *(const int4*)(row);
        int4 w1 = *(const int4*)(row + 4);
        int4 w2 = *(const int4*)(row + 8);
        int4 w3 = *(const int4*)(row + 12);
        __half2 v[16];
        v[0]  = VTh[((w0.x & 0xFFFF) << 9) + b2];
        v[1]  = VTh[((w0.y & 0xFFFF) << 9) + b2];
        v[2]  = VTh[((w0.z & 0xFFFF) << 9) + b2];
        v[3]  = VTh[((w0.w & 0xFFFF) << 9) + b2];
        v[4]  = VTh[((w1.x & 0xFFFF) << 9) + b2];
        v[5]  = VTh[((w1.y & 0xFFFF) << 9) + b2];
        v[6]  = VTh[((w1.z & 0xFFFF) << 9) + b2];
        v[7]  = VTh[((w1.w & 0xFFFF) << 9) + b2];
        v[8]  = VTh[((w2.x & 0xFFFF) << 9) + b2];
        v[9]  = VTh[((w2.y & 0xFFFF) << 9) + b2];
        v[10] = VTh[((w2.z & 0xFFFF) << 9) + b2];
        v[11] = VTh[((w2.w & 0xFFFF) << 9) + b2];
        v[12] = VTh[((w3.x & 0xFFFF) << 9) + b2];
        v[13] = VTh[((w3.y & 0xFFFF) << 9) + b2];
        v[14] = VTh[((w3.z & 0xFFFF) << 9) + b2];
        v[15] = VTh[((w3.w & 0xFFFF) << 9) + b2];
        int wt[16] = {w0.x >> 16, w0.y >> 16, w0.z >> 16, w0.w >> 16,
                      w1.x >> 16, w1.y >> 16, w1.z >> 16, w1.w >> 16,
                      w2.x >> 16, w2.y >> 16, w2.z >> 16, w2.w >> 16,
                      w3.x >> 16, w3.y >> 16, w3.z >> 16, w3.w >> 16};
        float2 a = make_float2(0.f, 0.f);
        #pragma unroll
        for (int j = 0; j < 16; ++j) {
            float wf = (float)wt[j];
            a.x += wf * __low2float(v[j]);
            a.y += wf * __high2float(v[j]);
        }
        int cnt = min(scnt[m], SMAX);                 // wave-uniform tail
        if (cnt > 16) {
            int jmax = (cnt + 3) & ~3;                // padded slots are zero -> safe
            for (int j = 16; j < jmax; j += 4) {
                int4 w = *(const int4*)(row + j);
                __half2 t0 = VTh[((w.x & 0xFFFF) << 9) + b2];
                __half2 t1 = VTh[((w.y & 0xFFFF) << 9) + b2];
                __half2 t2 = VTh[((w.z & 0xFFFF) << 9) + b2];
                __half2 t3 = VTh[((w.w & 0xFFFF) << 9) + b2];
                a.x += (float)(w.x >> 16) * __low2float(t0) + (float)(w.y >> 16) * __low2float(t1)
                     + (float)(w.z >> 16) * __low2float(t2) + (float)(w.w >> 16) * __low2float(t3);
                a.y += (float)(w.x >> 16) * __high2float(t0) + (float)(w.y >> 16) * __high2float(t1)
                     + (float)(w.z >> 16) * __high2float(t2) + (float)(w.w >> 16) * __high2float(t3);
            }
        }
        acc[mm] = a;
    }
    const int b = 2 * b2;
    *(float4*)(out + (size_t)b * Mm + m0) =
        make_float4(acc[0].x, acc[1].x, acc[2].x, acc[3].x);
    *(float4*)(out + (size_t)(b + 1) * Mm + m0) =
        make_float4(acc[0].y, acc[1].y, acc[2].y, acc[3].y);
}

// ---- fallback fused kernel (only if ws too small) ----
__global__ __launch_bounds__(256) void kinetic_fused(
    const float* __restrict__ conc, const float* __restrict__ kvec,
    const int* __restrict__ ecnt, const int* __restrict__ elist,
    const int* __restrict__ scnt, const int* __restrict__ slist,
    float* __restrict__ out)
{
    __shared__ float logc[Mm];
    __shared__ float vsh[Rr];
    const int b = blockIdx.x, t = threadIdx.x;
    const float4* c4 = (const float4*)(conc + (size_t)b * Mm);
    for (int i = t; i < Mm / 4; i += 256) {
        float4 c = c4[i];
        logc[4*i+0] = __logf(c.x); logc[4*i+1] = __logf(c.y);
        logc[4*i+2] = __logf(c.z); logc[4*i+3] = __logf(c.w);
    }
    __syncthreads();
    for (int r = t; r < Rr; r += 256) {
        int cnt = min(ecnt[r], EMAX);
        float s = 0.f;
        for (int j = 0; j < cnt; ++j) {
            int w = elist[r * EMAX + j];
            s += (float)(w >> 16) * logc[w & 0xFFFF];
        }
        vsh[r] = kvec[r] * __expf(s);
    }
    __syncthreads();
    for (int m = t; m < Mm; m += 256) {
        int cnt = min(scnt[m], SMAX);
        float acc = 0.f;
        for (int j = 0; j < cnt; ++j) {
            int w = slist[m * SMAX + j];
            acc += (float)(w >> 16) * vsh[w & 0xFFFF];
        }
        out[(size_t)b * Mm + m] = acc;
    }
}

extern "C" void kernel_launch(void* const* d_in, const int* in_sizes, int n_in,
                              void* d_out, int out_size, void* d_ws, size_t ws_size,
                              hipStream_t stream) {
    const float* conc = (const float*)d_in[0];
    const int*   E    = (const int*)d_in[1];
    const int*   S    = (const int*)d_in[2];
    const float* kvec = (const float*)d_in[3];
    float* out = (float*)d_out;

    // ws layout: VTh (16 MB fp16) | logcT (8 MB) | ecnt | scnt | elist | slist
    __half2* VTh  = (__half2*)d_ws;
    float* logcT  = (float*)((char*)d_ws + (size_t)Rr * Bsz * sizeof(__half));
    int*   ecnt   = (int*)(logcT + (size_t)Mm * Bsz);
    int*   scnt   = ecnt + Rr;
    int*   elist  = scnt + Mm;
    int*   slist  = elist + Rr * EMAX;
    const size_t need_lists = (size_t)(Rr + Mm + Rr * EMAX + Mm * SMAX) * sizeof(int);
    const size_t need_full  = (size_t)Rr * Bsz * sizeof(__half)
                            + (size_t)Mm * Bsz * sizeof(float) + need_lists;

    if (ws_size >= need_full) {
        transpose_log<<<(Mm / 64) * (Bsz / 64), 256, 0, stream>>>(
            conc, logcT, ecnt, (int4*)elist, (int4*)slist);
        build_lists<<<Mm, 256, 0, stream>>>(E, S, ecnt, elist, scnt, slist);
        rates_kernel<<<(Rr / 8) * (Bsz / 512), 256, 0, stream>>>(logcT, kvec, ecnt, elist, VTh);
        assemble_kernel<<<(Mm / 4) * (Bsz / 512), 256, 0, stream>>>(VTh, scnt, slist, out);
    } else if (ws_size >= need_lists) {
        int* ecnt2  = (int*)d_ws;
        int* scnt2  = ecnt2 + Rr;
        int* elist2 = scnt2 + Mm;
        int* slist2 = elist2 + Rr * EMAX;
        hipMemsetAsync(ecnt2, 0, (Rr + Mm) * sizeof(int), stream);
        build_lists<<<Mm, 256, 0, stream>>>(E, S, ecnt2, elist2, scnt2, slist2);
        kinetic_fused<<<Bsz, 256, 0, stream>>>(conc, kvec, ecnt2, elist2, scnt2, slist2, out);
    }
}